// Round 5
// baseline (531.109 us; speedup 1.0000x reference)
//
#include <hip/hip_runtime.h>
#include <cstdint>
#include <cstddef>

#define BATCH  8192
#define IN_N   256
#define OUT_N  256
#define LAT_N  128
#define SLABS  129                 // 128 latent slabs + 1 bw slab
#define KT     (SLABS * IN_N)      // 33024 = total K in elements
#define KT16   (KT / 16)           // 2064 k-tiles of 16
#define SPLITK 4

typedef _Float16 h8 __attribute__((ext_vector_type(8)));
typedef _Float16 h4 __attribute__((ext_vector_type(4)));
typedef float    f16v __attribute__((ext_vector_type(16)));
typedef float    f4v  __attribute__((ext_vector_type(4)));

// ws layout (bytes) — identical total footprint to the proven baseline (56,770,560 B)
#define WS_BP    0                 // packed B: 8 nt * 2064 kt * 64 lane * 8 halves * 2B = 16908288
#define WS_XH    16908288          // + 8192*256*2 = 4194304
#define WS_LT    21102592          // + 129*8192*2 = 2113536
#define WS_PARTS 23216128          // + 4 * 8192*256*4 = 33554432  -> total 56770560

// ---------------- K1 (fused prep): three independent jobs, one launch.
//  blocks [0, 2064)          : W transpose+pack into MFMA-fragment order
//  blocks [2064, 2064+6176)  : x->f16, latent->LT (transposed, +ones row)
//  blocks [8240, 8240+1024)  : bias part0[b][o] = latent[b]·Wb[:,o] + bb[o]
//
// Bp[nt][kt16][lane][h]  (lane = kh*32 + n32, h = 0..7)
//   = W2T[o = nt*32 + n32][k = kt16*16 + kh*8 + h]
// where W2T[o][k] = k<32768 ? Ww[k*256+o] : bw[(k-32768)*256+o]
#define PREP_T1   2064            // 516 * 4 transpose blocks
#define PREP_C1   8240            // + 6176 convert blocks
#define PREP_B1   9264            // + 1024 bias blocks
__global__ void k_prep(const float* __restrict__ Ww, const float* __restrict__ bw,
                       const float* __restrict__ x,  const float* __restrict__ latent,
                       const float* __restrict__ Wb, const float* __restrict__ bb,
                       _Float16* __restrict__ Bp, _Float16* __restrict__ Xh,
                       _Float16* __restrict__ LT, float* __restrict__ part0) {
    __shared__ float smem[64 * 65];         // transpose tile; bias branch reuses first 4KB
    const int bid = blockIdx.x;
    const int t   = threadIdx.x;

    if (bid < PREP_T1) {
        // ---- W transpose + f16 pack
        const int kx = bid % 516, oy = bid / 516;
        const int k0 = kx * 64;             // k tile (516*64 = 33024)
        const int o0 = oy * 64;             // o tile
        const int c  = t & 63, r0 = t >> 6;
        float (*tile)[65] = (float(*)[65])smem;
#pragma unroll
        for (int j = 0; j < 16; ++j) {
            int r = r0 + 4 * j;
            int k = k0 + r;
            float v;
            if (k < LAT_N * IN_N) v = Ww[(size_t)k * 256 + o0 + c];
            else                  v = bw[(size_t)(k - LAT_N * IN_N) * 256 + o0 + c];
            tile[r][c] = v;                 // tile[k - k0][o - o0]
        }
        __syncthreads();
        const int tl = t & 31, st = t >> 5;
        const int kt_l = st >> 1, nt_l = st & 1;
        const int nt   = oy * 2 + nt_l;     // 0..7
        const int kt16 = kx * 4 + kt_l;     // 0..2063
        _Float16* dst = Bp + ((size_t)(nt * KT16 + kt16) * 64) * 8;
#pragma unroll
        for (int kh = 0; kh < 2; ++kh) {
            h8 v;
#pragma unroll
            for (int h = 0; h < 8; ++h)
                v[h] = (_Float16)tile[kt_l * 16 + kh * 8 + h][nt_l * 32 + tl];
            *(h8*)(dst + (size_t)(kh * 32 + tl) * 8) = v;
        }
    } else if (bid < PREP_C1) {
        // ---- conversions
        const int cb = bid - PREP_T1;
        if (cb < 2048) {                    // x: 2M elems, 4 per thread
            int i = (cb * 256 + t) * 4;
            float4 v = *(const float4*)(x + i);
            h4 o;
            o[0] = (_Float16)v.x; o[1] = (_Float16)v.y;
            o[2] = (_Float16)v.z; o[3] = (_Float16)v.w;
            *(h4*)(Xh + i) = o;
        } else if (cb < 2048 + 4096) {      // latent transpose: 1M elems
            int i = (cb - 2048) * 256 + t;
            int b = i >> 7, l = i & 127;
            LT[(size_t)l * BATCH + b] = (_Float16)latent[i];
        } else {                            // ones row: 8192 elems
            int b = (cb - 2048 - 4096) * 256 + t;
            LT[(size_t)LAT_N * BATCH + b] = (_Float16)1.0f;
        }
    } else {
        // ---- bias into split-0 partial
        float (*lat)[128] = (float(*)[128])smem;
        const int b0 = (bid - PREP_C1) * 8; // 1024 blocks
#pragma unroll
        for (int j = 0; j < 4; ++j) {
            int idx = t + 256 * j;          // 0..1023
            int rr = idx >> 7, l = idx & 127;
            lat[rr][l] = latent[(size_t)(b0 + rr) * 128 + l];
        }
        __syncthreads();
        const int o = t;
        float acc[8];
        float bbv = bb[o];
#pragma unroll
        for (int rr = 0; rr < 8; ++rr) acc[rr] = bbv;
        for (int l = 0; l < 128; ++l) {
            float w = Wb[l * 256 + o];
#pragma unroll
            for (int rr = 0; rr < 8; ++rr) acc[rr] += lat[rr][l] * w;
        }
#pragma unroll
        for (int rr = 0; rr < 8; ++rr) part0[(size_t)(b0 + rr) * 256 + o] = acc[rr];
    }
}

// ---------------- K2: main GEMM. Block: 256 threads (4 waves), 128 rows x 128 cols,
// split over N (2) and K (4). Grid 512 = 64 m x 2 nb x 4 ks -> 2 blocks/CU
// (LDS 2x64KB = 128KB <= 160KB). Occupancy stays at the PROVEN no-spill regime
// (2 waves/SIMD, launch_bounds(256,2): ~115 arch VGPR + 64 acc AGPR ~= 180 < 256).
// ILP lever vs R2: each wave owns a 128x32 strip -> ONE 1KB B-fragment load feeds
// FOUR independent MFMAs (R2: 2 loads per 4 MFMAs). Memory ops per MFMA halve;
// B L2 traffic halves (~1.1GB total, ~135MB/XCD -> L2-resident slice of 2.1MB via
// bid&7 = (nb<<2)|ks XCD mapping).
__global__ __launch_bounds__(256, 2) void k_gemm(const _Float16* __restrict__ Bp,
                                                 const _Float16* __restrict__ Xh,
                                                 const _Float16* __restrict__ LT,
                                                 float* __restrict__ parts) {
    __shared__ _Float16 Xs[128 * 256];      // 64 KB

    const int bid   = blockIdx.x;           // 512 blocks
    const int ks    = bid & 3;
    const int nb    = (bid >> 2) & 1;
    const int m_blk = bid >> 3;             // 0..63
    const int m0    = m_blk * 128;
    const int slab0 = (ks == 0) ? 0 : 33 + 32 * (ks - 1);
    const int nslab = (ks == 0) ? 33 : 32;  // 33 + 3*32 = 129

    const int tid = threadIdx.x, wid = tid >> 6, lane = tid & 63;
    const int l32 = lane & 31, khalf = lane >> 5;

    // ---- stage X tile into LDS with 16B-granule XOR swizzle (granule g stored at slot g^(m&7))
    for (int j = 0; j < 16; ++j) {
        int G = j * 256 + tid;              // 4096 granules total
        int m = G >> 5, gp = G & 31;
        int g = gp ^ (m & 7);
        h8 v = *(const h8*)(Xh + (size_t)(m0 + m) * IN_N + g * 8);
        *(h8*)(Xs + m * IN_N + gp * 8) = v;
    }
    __syncthreads();

    // per-lane rows (A side): m = t*32 + l32, t in 0..3
    int mrow[4], m7[4], pbase[4], m6[4];
#pragma unroll
    for (int t = 0; t < 4; ++t) {
        mrow[t]  = t * 32 + l32;
        m7[t]    = mrow[t] & 7;
        m6[t]    = m7[t] & 6;
        pbase[t] = mrow[t] * IN_N + (khalf ^ (m7[t] & 1)) * 8;
    }

    // latent scalars for this block's rows
    const _Float16* ltp = LT + (size_t)slab0 * BATCH + m0;
    _Float16 s_cur[4], s_nxt[4];
#pragma unroll
    for (int t = 0; t < 4; ++t) s_cur[t] = ltp[mrow[t]];

    // B pointer (packed layout): this wave's col-tile nt = nb*4 + wid; fragment for
    // (nt, k-tile kt) at Bp + ((nt*KT16 + kt)*64 + lane)*8 -- lane-contiguous 16B.
    const int nt = nb * 4 + wid;
    const _Float16* bp = Bp + ((size_t)(nt * KT16 + slab0 * 16) * 64 + lane) * 8;

    f16v acc[4];
#pragma unroll
    for (int t = 0; t < 4; ++t)
#pragma unroll
        for (int r = 0; r < 16; ++r) acc[t][r] = 0.0f;

    for (int sl = 0; sl < nslab; ++sl) {
        if (sl) {
#pragma unroll
            for (int t = 0; t < 4; ++t) s_cur[t] = s_nxt[t];
        }
        if (sl + 1 < nslab) {
            const _Float16* p = ltp + (size_t)(sl + 1) * BATCH;
#pragma unroll
            for (int t = 0; t < 4; ++t) s_nxt[t] = p[mrow[t]];
        }
        h8 s8[4];
#pragma unroll
        for (int t = 0; t < 4; ++t) {
            _Float16 s = s_cur[t];
            s8[t][0]=s; s8[t][1]=s; s8[t][2]=s; s8[t][3]=s;
            s8[t][4]=s; s8[t][5]=s; s8[t][6]=s; s8[t][7]=s;
        }
        const _Float16* bsl = bp + (size_t)sl * (16 * 512);
#pragma unroll
        for (int ks16 = 0; ks16 < 16; ++ks16) {
            h8 b = *(const h8*)(bsl + ks16 * 512);
            h8 a[4];
#pragma unroll
            for (int t = 0; t < 4; ++t) {
                int off = pbase[t] + ((ks16 * 2) ^ m6[t]) * 8;
                h8 xv = *(const h8*)(Xs + off);
                a[t] = xv * s8[t];
            }
#pragma unroll
            for (int t = 0; t < 4; ++t)
                acc[t] = __builtin_amdgcn_mfma_f32_32x32x16_f16(a[t], b, acc[t], 0, 0, 0);
        }
    }

    // epilogue: write partials; split 0 accumulates onto pre-written bias
    float* dst = parts + (size_t)ks * ((size_t)BATCH * OUT_N);
#pragma unroll
    for (int t = 0; t < 4; ++t) {
        int rowb = m0 + t * 32;
        int col  = nb * 128 + wid * 32 + l32;
#pragma unroll
        for (int r = 0; r < 16; ++r) {
            int row = rowb + (r & 3) + 8 * (r >> 2) + 4 * khalf;
            size_t off = (size_t)row * OUT_N + col;
            float v = acc[t][r];
            if (ks == 0) dst[off] += v;
            else         dst[off] = v;
        }
    }
}

// ---------------- K3: out = sum of 4 partials
__global__ void k_reduce(const float* __restrict__ parts, float* __restrict__ out) {
    int i = (blockIdx.x * 256 + threadIdx.x) * 4;
    f4v s = *(const f4v*)(parts + i);
    s += *(const f4v*)(parts + 2097152 + i);
    s += *(const f4v*)(parts + 2 * 2097152 + i);
    s += *(const f4v*)(parts + 3 * 2097152 + i);
    *(f4v*)(out + i) = s;
}

extern "C" void kernel_launch(void* const* d_in, const int* in_sizes, int n_in,
                              void* d_out, int out_size, void* d_ws, size_t ws_size,
                              hipStream_t stream) {
    const float* x      = (const float*)d_in[0];
    const float* latent = (const float*)d_in[1];
    const float* Ww     = (const float*)d_in[2];
    const float* bw     = (const float*)d_in[3];
    const float* Wb     = (const float*)d_in[4];
    const float* bb     = (const float*)d_in[5];

    char* ws = (char*)d_ws;
    _Float16* Bp    = (_Float16*)(ws + WS_BP);
    _Float16* Xh    = (_Float16*)(ws + WS_XH);
    _Float16* LT    = (_Float16*)(ws + WS_LT);
    float*    parts = (float*)(ws + WS_PARTS);
    float*    out   = (float*)d_out;

    k_prep<<<PREP_B1, 256, 0, stream>>>(Ww, bw, x, latent, Wb, bb, Bp, Xh, LT, parts);
    k_gemm<<<512, 256, 0, stream>>>(Bp, Xh, LT, parts);
    k_reduce<<<2048, 256, 0, stream>>>(parts, out);
}

// Round 6
// 497.021 us; speedup vs baseline: 1.0686x; 1.0686x over previous
//
#include <hip/hip_runtime.h>
#include <cstdint>
#include <cstddef>

#define BATCH  8192
#define IN_N   256
#define OUT_N  256
#define LAT_N  128
#define SLABS  129                 // 128 latent slabs + 1 bw slab
#define KT     (SLABS * IN_N)      // 33024 = total K in elements
#define KT16   (KT / 16)           // 2064 k-tiles of 16
#define SPLITK 4

typedef _Float16 h8 __attribute__((ext_vector_type(8)));
typedef _Float16 h4 __attribute__((ext_vector_type(4)));
typedef float    f16v __attribute__((ext_vector_type(16)));
typedef float    f4v  __attribute__((ext_vector_type(4)));

// ws layout (bytes) — identical total footprint to the proven baseline (56,770,560 B)
#define WS_BP    0                 // packed B: 8 nt * 2064 kt * 64 lane * 8 halves * 2B = 16908288
#define WS_XH    16908288          // + 8192*256*2 = 4194304
#define WS_LT    21102592          // + 129*8192*2 = 2113536
#define WS_PARTS 23216128          // + 4 * 8192*256*4 = 33554432  -> total 56770560

// ---------------- K1 (fused prep): three independent jobs, one launch.
//  blocks [0, 2064)          : W transpose+pack into MFMA-fragment order
//  blocks [2064, 2064+6176)  : x->f16, latent->LT (transposed, +ones row)
//  blocks [8240, 8240+1024)  : bias part0[b][o] = latent[b]·Wb[:,o] + bb[o]
//
// Bp[nt][kt16][lane][h]  (lane = kh*32 + n32, h = 0..7)
//   = W2T[o = nt*32 + n32][k = kt16*16 + kh*8 + h]
// where W2T[o][k] = k<32768 ? Ww[k*256+o] : bw[(k-32768)*256+o]
#define PREP_T1   2064            // 516 * 4 transpose blocks
#define PREP_C1   8240            // + 6176 convert blocks
#define PREP_B1   9264            // + 1024 bias blocks
__global__ void k_prep(const float* __restrict__ Ww, const float* __restrict__ bw,
                       const float* __restrict__ x,  const float* __restrict__ latent,
                       const float* __restrict__ Wb, const float* __restrict__ bb,
                       _Float16* __restrict__ Bp, _Float16* __restrict__ Xh,
                       _Float16* __restrict__ LT, float* __restrict__ part0) {
    __shared__ float smem[64 * 65];         // transpose tile; bias branch reuses first 4KB
    const int bid = blockIdx.x;
    const int t   = threadIdx.x;

    if (bid < PREP_T1) {
        // ---- W transpose + f16 pack
        const int kx = bid % 516, oy = bid / 516;
        const int k0 = kx * 64;             // k tile (516*64 = 33024)
        const int o0 = oy * 64;             // o tile
        const int c  = t & 63, r0 = t >> 6;
        float (*tile)[65] = (float(*)[65])smem;
#pragma unroll
        for (int j = 0; j < 16; ++j) {
            int r = r0 + 4 * j;
            int k = k0 + r;
            float v;
            if (k < LAT_N * IN_N) v = Ww[(size_t)k * 256 + o0 + c];
            else                  v = bw[(size_t)(k - LAT_N * IN_N) * 256 + o0 + c];
            tile[r][c] = v;                 // tile[k - k0][o - o0]
        }
        __syncthreads();
        const int tl = t & 31, st = t >> 5;
        const int kt_l = st >> 1, nt_l = st & 1;
        const int nt   = oy * 2 + nt_l;     // 0..7
        const int kt16 = kx * 4 + kt_l;     // 0..2063
        _Float16* dst = Bp + ((size_t)(nt * KT16 + kt16) * 64) * 8;
#pragma unroll
        for (int kh = 0; kh < 2; ++kh) {
            h8 v;
#pragma unroll
            for (int h = 0; h < 8; ++h)
                v[h] = (_Float16)tile[kt_l * 16 + kh * 8 + h][nt_l * 32 + tl];
            *(h8*)(dst + (size_t)(kh * 32 + tl) * 8) = v;
        }
    } else if (bid < PREP_C1) {
        // ---- conversions
        const int cb = bid - PREP_T1;
        if (cb < 2048) {                    // x: 2M elems, 4 per thread
            int i = (cb * 256 + t) * 4;
            float4 v = *(const float4*)(x + i);
            h4 o;
            o[0] = (_Float16)v.x; o[1] = (_Float16)v.y;
            o[2] = (_Float16)v.z; o[3] = (_Float16)v.w;
            *(h4*)(Xh + i) = o;
        } else if (cb < 2048 + 4096) {      // latent transpose: 1M elems
            int i = (cb - 2048) * 256 + t;
            int b = i >> 7, l = i & 127;
            LT[(size_t)l * BATCH + b] = (_Float16)latent[i];
        } else {                            // ones row: 8192 elems
            int b = (cb - 2048 - 4096) * 256 + t;
            LT[(size_t)LAT_N * BATCH + b] = (_Float16)1.0f;
        }
    } else {
        // ---- bias into split-0 partial
        float (*lat)[128] = (float(*)[128])smem;
        const int b0 = (bid - PREP_C1) * 8; // 1024 blocks
#pragma unroll
        for (int j = 0; j < 4; ++j) {
            int idx = t + 256 * j;          // 0..1023
            int rr = idx >> 7, l = idx & 127;
            lat[rr][l] = latent[(size_t)(b0 + rr) * 128 + l];
        }
        __syncthreads();
        const int o = t;
        float acc[8];
        float bbv = bb[o];
#pragma unroll
        for (int rr = 0; rr < 8; ++rr) acc[rr] = bbv;
        for (int l = 0; l < 128; ++l) {
            float w = Wb[l * 256 + o];
#pragma unroll
            for (int rr = 0; rr < 8; ++rr) acc[rr] += lat[rr][l] * w;
        }
#pragma unroll
        for (int rr = 0; rr < 8; ++rr) part0[(size_t)(b0 + rr) * 256 + o] = acc[rr];
    }
}

// ---------------- K2: main GEMM. Block: 256 threads (4 waves), 128 rows x 128 cols,
// split over N (2) and K (4). Grid 512 = 64 m x 2 nb x 4 ks.
// REGISTER LESSON (R3/R4/R5): any __launch_bounds__ min-waves >= 2 makes the
// allocator clamp to the next occupancy granule (64/128 regs) and SPILL (700+ MB
// scratch). min-waves = 1 is the only proven no-spill regime (R0: 248 regs).
// At the expected ~200-250 total regs (<= 256) and LDS 64KB, the HARDWARE still
// co-schedules 2 blocks/CU = 2 waves/SIMD — occupancy comes from the runtime,
// not the bound. Each wave owns a 128x32 strip: ONE 1KB B-fragment load feeds
// FOUR independent MFMAs; full 16-deep unrolled k-loop keeps many B loads in
// flight (that's the latency-hiding, register file used as prefetch buffer).
// bid&7 = (nb<<2)|ks -> each XCD reads a 2.1MB B slice (L2-resident).
__global__ __launch_bounds__(256, 1) void k_gemm(const _Float16* __restrict__ Bp,
                                                 const _Float16* __restrict__ Xh,
                                                 const _Float16* __restrict__ LT,
                                                 float* __restrict__ parts) {
    __shared__ _Float16 Xs[128 * 256];      // 64 KB

    const int bid   = blockIdx.x;           // 512 blocks
    const int ks    = bid & 3;
    const int nb    = (bid >> 2) & 1;
    const int m_blk = bid >> 3;             // 0..63
    const int m0    = m_blk * 128;
    const int slab0 = (ks == 0) ? 0 : 33 + 32 * (ks - 1);
    const int nslab = (ks == 0) ? 33 : 32;  // 33 + 3*32 = 129

    const int tid = threadIdx.x, wid = tid >> 6, lane = tid & 63;
    const int l32 = lane & 31, khalf = lane >> 5;

    // ---- stage X tile into LDS with 16B-granule XOR swizzle (granule g stored at slot g^(m&7))
    for (int j = 0; j < 16; ++j) {
        int G = j * 256 + tid;              // 4096 granules total
        int m = G >> 5, gp = G & 31;
        int g = gp ^ (m & 7);
        h8 v = *(const h8*)(Xh + (size_t)(m0 + m) * IN_N + g * 8);
        *(h8*)(Xs + m * IN_N + gp * 8) = v;
    }
    __syncthreads();

    // per-lane rows (A side): m = t*32 + l32, t in 0..3
    int mrow[4], m7[4], pbase[4], m6[4];
#pragma unroll
    for (int t = 0; t < 4; ++t) {
        mrow[t]  = t * 32 + l32;
        m7[t]    = mrow[t] & 7;
        m6[t]    = m7[t] & 6;
        pbase[t] = mrow[t] * IN_N + (khalf ^ (m7[t] & 1)) * 8;
    }

    // latent scalars for this block's rows
    const _Float16* ltp = LT + (size_t)slab0 * BATCH + m0;
    _Float16 s_cur[4], s_nxt[4];
#pragma unroll
    for (int t = 0; t < 4; ++t) s_cur[t] = ltp[mrow[t]];

    // B pointer (packed layout): this wave's col-tile nt = nb*4 + wid; fragment for
    // (nt, k-tile kt) at Bp + ((nt*KT16 + kt)*64 + lane)*8 -- lane-contiguous 16B.
    const int nt = nb * 4 + wid;
    const _Float16* bp = Bp + ((size_t)(nt * KT16 + slab0 * 16) * 64 + lane) * 8;

    f16v acc[4];
#pragma unroll
    for (int t = 0; t < 4; ++t)
#pragma unroll
        for (int r = 0; r < 16; ++r) acc[t][r] = 0.0f;

    for (int sl = 0; sl < nslab; ++sl) {
        if (sl) {
#pragma unroll
            for (int t = 0; t < 4; ++t) s_cur[t] = s_nxt[t];
        }
        if (sl + 1 < nslab) {
            const _Float16* p = ltp + (size_t)(sl + 1) * BATCH;
#pragma unroll
            for (int t = 0; t < 4; ++t) s_nxt[t] = p[mrow[t]];
        }
        h8 s8[4];
#pragma unroll
        for (int t = 0; t < 4; ++t) {
            _Float16 s = s_cur[t];
            s8[t][0]=s; s8[t][1]=s; s8[t][2]=s; s8[t][3]=s;
            s8[t][4]=s; s8[t][5]=s; s8[t][6]=s; s8[t][7]=s;
        }
        const _Float16* bsl = bp + (size_t)sl * (16 * 512);
#pragma unroll
        for (int ks16 = 0; ks16 < 16; ++ks16) {
            h8 b = *(const h8*)(bsl + ks16 * 512);
            h8 a[4];
#pragma unroll
            for (int t = 0; t < 4; ++t) {
                int off = pbase[t] + ((ks16 * 2) ^ m6[t]) * 8;
                h8 xv = *(const h8*)(Xs + off);
                a[t] = xv * s8[t];
            }
#pragma unroll
            for (int t = 0; t < 4; ++t)
                acc[t] = __builtin_amdgcn_mfma_f32_32x32x16_f16(a[t], b, acc[t], 0, 0, 0);
        }
    }

    // epilogue: write partials; split 0 accumulates onto pre-written bias
    float* dst = parts + (size_t)ks * ((size_t)BATCH * OUT_N);
#pragma unroll
    for (int t = 0; t < 4; ++t) {
        int rowb = m0 + t * 32;
        int col  = nb * 128 + wid * 32 + l32;
#pragma unroll
        for (int r = 0; r < 16; ++r) {
            int row = rowb + (r & 3) + 8 * (r >> 2) + 4 * khalf;
            size_t off = (size_t)row * OUT_N + col;
            float v = acc[t][r];
            if (ks == 0) dst[off] += v;
            else         dst[off] = v;
        }
    }
}

// ---------------- K3: out = sum of 4 partials
__global__ void k_reduce(const float* __restrict__ parts, float* __restrict__ out) {
    int i = (blockIdx.x * 256 + threadIdx.x) * 4;
    f4v s = *(const f4v*)(parts + i);
    s += *(const f4v*)(parts + 2097152 + i);
    s += *(const f4v*)(parts + 2 * 2097152 + i);
    s += *(const f4v*)(parts + 3 * 2097152 + i);
    *(f4v*)(out + i) = s;
}

extern "C" void kernel_launch(void* const* d_in, const int* in_sizes, int n_in,
                              void* d_out, int out_size, void* d_ws, size_t ws_size,
                              hipStream_t stream) {
    const float* x      = (const float*)d_in[0];
    const float* latent = (const float*)d_in[1];
    const float* Ww     = (const float*)d_in[2];
    const float* bw     = (const float*)d_in[3];
    const float* Wb     = (const float*)d_in[4];
    const float* bb     = (const float*)d_in[5];

    char* ws = (char*)d_ws;
    _Float16* Bp    = (_Float16*)(ws + WS_BP);
    _Float16* Xh    = (_Float16*)(ws + WS_XH);
    _Float16* LT    = (_Float16*)(ws + WS_LT);
    float*    parts = (float*)(ws + WS_PARTS);
    float*    out   = (float*)d_out;

    k_prep<<<PREP_B1, 256, 0, stream>>>(Ww, bw, x, latent, Wb, bb, Bp, Xh, LT, parts);
    k_gemm<<<512, 256, 0, stream>>>(Bp, Xh, LT, parts);
    k_reduce<<<2048, 256, 0, stream>>>(parts, out);
}

// Round 7
// 273.134 us; speedup vs baseline: 1.9445x; 1.8197x over previous
//
#include <hip/hip_runtime.h>
#include <cstdint>
#include <cstddef>

#define BATCH  8192
#define IN_N   256
#define OUT_N  256
#define LAT_N  128
#define SLABS  129                 // 128 latent slabs + 1 bw slab
#define KT     (SLABS * IN_N)      // 33024 = total K in elements
#define KT16   (KT / 16)           // 2064 k-tiles of 16
#define SPLITK 4

typedef _Float16 h8 __attribute__((ext_vector_type(8)));
typedef _Float16 h4 __attribute__((ext_vector_type(4)));
typedef _Float16 h2 __attribute__((ext_vector_type(2)));
typedef float    f16v __attribute__((ext_vector_type(16)));
typedef float    f4v  __attribute__((ext_vector_type(4)));

// ws layout (bytes) — identical total footprint to the proven baseline (56,770,560 B)
#define WS_BP    0                 // packed B: 8 nt * 2064 kt * 64 lane * 8 halves * 2B = 16908288
#define WS_XH    16908288          // + 8192*256*2 = 4194304
#define WS_LT    21102592          // + 129*8192*2 = 2113536
#define WS_PARTS 23216128          // + 4 * 8192*256*4 = 33554432  -> total 56770560

// ---------------- K1 (fused prep), fully-coalesced rewrite. Block ranges:
//  [0, 516)        W transpose+pack:  block = 64 k-rows x 256 o. Read = 64x 1KB
//                  coalesced float4 rows into 32KB f16 LDS tile; pack = coalesced
//                  512B fragment stores. (old: 256B wave segments + f32 LDS)
//  [516, 580)      latent transpose via 128x129 LDS tile (old: 2B/lane @16KB-stride
//                  global scatter — 64-way). Reads float4-coalesced, writes 256B rows.
//  [580, 1604)     x -> f16, h8 per thread (32B/lane reads)
//  [1604, 1608)    ones row of LT
//  [1608, 2632)    bias part0[b][o] = latent[b]·Wb[:,o] + bb[o]
//
// Bp[nt][kt16][lane = kh*32+tl][h] = W2T[o = nt*32+tl][k = kt16*16 + kh*8 + h]
// where W2T[o][k] = k<32768 ? Ww[k*256+o] : bw[(k-32768)*256+o]
#define PR_T1   516
#define PR_L1   580
#define PR_X1   1604
#define PR_O1   1608
#define PR_B1   2632
__global__ void k_prep(const float* __restrict__ Ww, const float* __restrict__ bw,
                       const float* __restrict__ x,  const float* __restrict__ latent,
                       const float* __restrict__ Wb, const float* __restrict__ bb,
                       _Float16* __restrict__ Bp, _Float16* __restrict__ Xh,
                       _Float16* __restrict__ LT, float* __restrict__ part0) {
    __shared__ _Float16 smemh[16512];       // 33024 B: max(transpose 32KB, latT 33KB, bias 4KB)
    const int bid = blockIdx.x;
    const int t   = threadIdx.x;

    if (bid < PR_T1) {
        // ---- W transpose + pack. tile[64][256] f16 = 32KB.
        _Float16* tile = smemh;
        const int k0 = bid * 64;
#pragma unroll
        for (int j = 0; j < 16; ++j) {
            int idx = j * 256 + t;          // 4096 float4 slots = 64 rows x 64 f4
            int row = idx >> 6, col = (idx & 63) * 4;
            int k = k0 + row;
            const float* src = (k < LAT_N * IN_N)
                             ? Ww + (size_t)k * 256 + col
                             : bw + (size_t)(k - LAT_N * IN_N) * 256 + col;
            float4 v = *(const float4*)src;
            h4 o;
            o[0] = (_Float16)v.x; o[1] = (_Float16)v.y;
            o[2] = (_Float16)v.z; o[3] = (_Float16)v.w;
            *(h4*)(tile + row * 256 + col) = o;
        }
        __syncthreads();
        const int tl = t & 31;
#pragma unroll
        for (int j = 0; j < 4; ++j) {
            int stid = j * 8 + (t >> 5);    // 0..31 subtiles
            int kt_l = stid >> 3, nt = stid & 7;
            int kt16 = bid * 4 + kt_l;
            _Float16* dst = Bp + ((size_t)(nt * KT16 + kt16) * 64) * 8;
#pragma unroll
            for (int kh = 0; kh < 2; ++kh) {
                h8 v;
#pragma unroll
                for (int h = 0; h < 8; ++h)
                    v[h] = tile[(kt_l * 16 + kh * 8 + h) * 256 + nt * 32 + tl];
                *(h8*)(dst + (size_t)(kh * 32 + tl) * 8) = v;
            }
        }
    } else if (bid < PR_L1) {
        // ---- latent transpose: t2[128 l][129 pad] f16; b-range b0..b0+127
        _Float16* t2 = smemh;
        const int b0 = (bid - PR_T1) * 128;
#pragma unroll
        for (int j = 0; j < 16; ++j) {
            int idx = j * 256 + t;          // 4096 float4 slots = 128 b-rows x 32 f4
            int b = idx >> 5, l = (idx & 31) * 4;
            float4 v = *(const float4*)(latent + (size_t)(b0 + b) * 128 + l);
            t2[(l + 0) * 129 + b] = (_Float16)v.x;
            t2[(l + 1) * 129 + b] = (_Float16)v.y;
            t2[(l + 2) * 129 + b] = (_Float16)v.z;
            t2[(l + 3) * 129 + b] = (_Float16)v.w;
        }
        __syncthreads();
#pragma unroll
        for (int j = 0; j < 32; ++j) {
            int idx = j * 256 + t;          // 8192 h2 slots = 128 l-rows x 64 h2
            int l = idx >> 6, bb = (idx & 63) * 2;
            h2 w;
            w[0] = t2[l * 129 + bb];
            w[1] = t2[l * 129 + bb + 1];
            *(h2*)(LT + (size_t)l * BATCH + b0 + bb) = w;
        }
    } else if (bid < PR_X1) {
        // ---- x -> f16, 8 elems/thread
        const int cb = bid - PR_L1;
        int i = (cb * 256 + t) * 8;
        float4 v0 = *(const float4*)(x + i);
        float4 v1 = *(const float4*)(x + i + 4);
        h8 o;
        o[0] = (_Float16)v0.x; o[1] = (_Float16)v0.y;
        o[2] = (_Float16)v0.z; o[3] = (_Float16)v0.w;
        o[4] = (_Float16)v1.x; o[5] = (_Float16)v1.y;
        o[6] = (_Float16)v1.z; o[7] = (_Float16)v1.w;
        *(h8*)(Xh + i) = o;
    } else if (bid < PR_O1) {
        // ---- ones row l=128 of LT
        const int ob = bid - PR_X1;
        int base = ob * 2048 + t * 8;
        h8 o;
#pragma unroll
        for (int h = 0; h < 8; ++h) o[h] = (_Float16)1.0f;
        *(h8*)(LT + (size_t)LAT_N * BATCH + base) = o;
    } else {
        // ---- bias into split-0 partial
        float* lat = (float*)smemh;         // [8][128] f32 = 4KB
        const int b0 = (bid - PR_O1) * 8;   // 1024 blocks
#pragma unroll
        for (int j = 0; j < 4; ++j) {
            int idx = t + 256 * j;          // 0..1023
            int rr = idx >> 7, l = idx & 127;
            lat[rr * 128 + l] = latent[(size_t)(b0 + rr) * 128 + l];
        }
        __syncthreads();
        const int o = t;
        float acc[8];
        float bbv = bb[o];
#pragma unroll
        for (int rr = 0; rr < 8; ++rr) acc[rr] = bbv;
        for (int l = 0; l < 128; ++l) {
            float w = Wb[l * 256 + o];
#pragma unroll
            for (int rr = 0; rr < 8; ++rr) acc[rr] += lat[rr * 128 + l] * w;
        }
#pragma unroll
        for (int rr = 0; rr < 8; ++rr) part0[(size_t)(b0 + rr) * 256 + o] = acc[rr];
    }
}

// ---------------- K2: main GEMM — EXACT R2 kernel (proven 176us, 787 TF, no spill).
// Block: 256 threads (4 waves), 64 rows x 256 cols, split-K=4. Grid 512 -> 2 blocks/CU
// (LDS 2x32KB); VGPR 120 arch + 64 acc = 184 <= 256 -> 2 waves/SIMD.
// REGISTER MAP (R3-R6 lessons): (X,>=2) with demand>granule => clamp+spill;
// (X,1) => allocator overshoots 256 (R6: 264). This config is the ONLY proven
// no-spill 2-waves/SIMD point. Do not perturb its register pressure.
__global__ __launch_bounds__(256, 2) void k_gemm(const _Float16* __restrict__ Bp,
                                                 const _Float16* __restrict__ Xh,
                                                 const _Float16* __restrict__ LT,
                                                 float* __restrict__ parts) {
    __shared__ _Float16 Xs[64 * 256];       // 32 KB

    const int bid   = blockIdx.x;           // 512 blocks
    const int m_blk = bid >> 2;             // 0..127
    const int ks    = bid & 3;
    const int m0    = m_blk * 64;
    const int slab0 = (ks == 0) ? 0 : 33 + 32 * (ks - 1);
    const int nslab = (ks == 0) ? 33 : 32;  // 33 + 3*32 = 129

    const int tid = threadIdx.x, wid = tid >> 6, lane = tid & 63;
    const int l32 = lane & 31, khalf = lane >> 5;

    // ---- stage X tile into LDS with 16B-granule XOR swizzle (granule g stored at slot g^(m&7))
    for (int j = 0; j < 8; ++j) {
        int G = j * 256 + tid;              // 2048 granules total
        int m = G >> 5, gp = G & 31;
        int g = gp ^ (m & 7);
        h8 v = *(const h8*)(Xh + (size_t)(m0 + m) * IN_N + g * 8);
        *(h8*)(Xs + m * IN_N + gp * 8) = v;
    }
    __syncthreads();

    // per-lane rows (A side): m = t*32 + l32, t in {0,1}
    int mrow[2], m7[2], pbase[2], m6[2];
#pragma unroll
    for (int t = 0; t < 2; ++t) {
        mrow[t]  = t * 32 + l32;
        m7[t]    = mrow[t] & 7;
        m6[t]    = m7[t] & 6;
        pbase[t] = mrow[t] * IN_N + (khalf ^ (m7[t] & 1)) * 8;
    }

    // latent scalars for this block's rows
    const _Float16* ltp = LT + (size_t)slab0 * BATCH + m0;
    _Float16 s_cur[2], s_nxt[2];
#pragma unroll
    for (int t = 0; t < 2; ++t) s_cur[t] = ltp[mrow[t]];

    // B pointers (packed layout): fragment for (col-tile nt, k-tile kt) at
    // Bp + ((nt*KT16 + kt)*64 + lane)*8  -- lane-contiguous 16B each.
    const _Float16* bp0 = Bp + ((size_t)((wid * 2 + 0) * KT16 + slab0 * 16) * 64 + lane) * 8;
    const _Float16* bp1 = Bp + ((size_t)((wid * 2 + 1) * KT16 + slab0 * 16) * 64 + lane) * 8;

    f16v acc[2][2];
#pragma unroll
    for (int t = 0; t < 2; ++t)
#pragma unroll
        for (int u = 0; u < 2; ++u)
#pragma unroll
            for (int r = 0; r < 16; ++r) acc[t][u][r] = 0.0f;

    for (int sl = 0; sl < nslab; ++sl) {
        if (sl) {
#pragma unroll
            for (int t = 0; t < 2; ++t) s_cur[t] = s_nxt[t];
        }
        if (sl + 1 < nslab) {
            const _Float16* p = ltp + (size_t)(sl + 1) * BATCH;
#pragma unroll
            for (int t = 0; t < 2; ++t) s_nxt[t] = p[mrow[t]];
        }
        h8 s8[2];
#pragma unroll
        for (int t = 0; t < 2; ++t) {
            _Float16 s = s_cur[t];
            s8[t][0]=s; s8[t][1]=s; s8[t][2]=s; s8[t][3]=s;
            s8[t][4]=s; s8[t][5]=s; s8[t][6]=s; s8[t][7]=s;
        }
        const _Float16* b0p = bp0 + (size_t)sl * (16 * 512);
        const _Float16* b1p = bp1 + (size_t)sl * (16 * 512);
#pragma unroll
        for (int ks16 = 0; ks16 < 16; ++ks16) {
            h8 b0 = *(const h8*)(b0p + ks16 * 512);
            h8 b1 = *(const h8*)(b1p + ks16 * 512);
            h8 a[2];
#pragma unroll
            for (int t = 0; t < 2; ++t) {
                int off = pbase[t] + ((ks16 * 2) ^ m6[t]) * 8;
                h8 xv = *(const h8*)(Xs + off);
                a[t] = xv * s8[t];
            }
#pragma unroll
            for (int t = 0; t < 2; ++t) {
                acc[t][0] = __builtin_amdgcn_mfma_f32_32x32x16_f16(a[t], b0, acc[t][0], 0, 0, 0);
                acc[t][1] = __builtin_amdgcn_mfma_f32_32x32x16_f16(a[t], b1, acc[t][1], 0, 0, 0);
            }
        }
    }

    // epilogue: write partials; split 0 accumulates onto pre-written bias
    float* dst = parts + (size_t)ks * ((size_t)BATCH * OUT_N);
#pragma unroll
    for (int t = 0; t < 2; ++t) {
        int rowb = m0 + t * 32;
#pragma unroll
        for (int u = 0; u < 2; ++u) {
            int col = wid * 64 + u * 32 + l32;
#pragma unroll
            for (int r = 0; r < 16; ++r) {
                int row = rowb + (r & 3) + 8 * (r >> 2) + 4 * khalf;
                size_t off = (size_t)row * OUT_N + col;
                float v = acc[t][u][r];
                if (ks == 0) dst[off] += v;
                else         dst[off] = v;
            }
        }
    }
}

// ---------------- K3: out = sum of 4 partials
__global__ void k_reduce(const float* __restrict__ parts, float* __restrict__ out) {
    int i = (blockIdx.x * 256 + threadIdx.x) * 4;
    f4v s = *(const f4v*)(parts + i);
    s += *(const f4v*)(parts + 2097152 + i);
    s += *(const f4v*)(parts + 2 * 2097152 + i);
    s += *(const f4v*)(parts + 3 * 2097152 + i);
    *(f4v*)(out + i) = s;
}

extern "C" void kernel_launch(void* const* d_in, const int* in_sizes, int n_in,
                              void* d_out, int out_size, void* d_ws, size_t ws_size,
                              hipStream_t stream) {
    const float* x      = (const float*)d_in[0];
    const float* latent = (const float*)d_in[1];
    const float* Ww     = (const float*)d_in[2];
    const float* bw     = (const float*)d_in[3];
    const float* Wb     = (const float*)d_in[4];
    const float* bb     = (const float*)d_in[5];

    char* ws = (char*)d_ws;
    _Float16* Bp    = (_Float16*)(ws + WS_BP);
    _Float16* Xh    = (_Float16*)(ws + WS_XH);
    _Float16* LT    = (_Float16*)(ws + WS_LT);
    float*    parts = (float*)(ws + WS_PARTS);
    float*    out   = (float*)d_out;

    k_prep<<<PR_B1, 256, 0, stream>>>(Ww, bw, x, latent, Wb, bb, Bp, Xh, LT, parts);
    k_gemm<<<512, 256, 0, stream>>>(Bp, Xh, LT, parts);
    k_reduce<<<2048, 256, 0, stream>>>(parts, out);
}

// Round 8
// 252.207 us; speedup vs baseline: 2.1058x; 1.0830x over previous
//
#include <hip/hip_runtime.h>
#include <cstdint>
#include <cstddef>

#define BATCH  8192
#define IN_N   256
#define OUT_N  256
#define LAT_N  128
#define SLABS  129                 // 128 latent slabs + 1 bw slab
#define KT     (SLABS * IN_N)      // 33024 = total K in elements
#define KT16   (KT / 16)           // 2064 k-tiles of 16
#define SPLITK 4

typedef _Float16 h8 __attribute__((ext_vector_type(8)));
typedef _Float16 h4 __attribute__((ext_vector_type(4)));
typedef _Float16 h2 __attribute__((ext_vector_type(2)));
typedef float    f16v __attribute__((ext_vector_type(16)));
typedef float    f4v  __attribute__((ext_vector_type(4)));

#define AS1 __attribute__((address_space(1)))
#define AS3 __attribute__((address_space(3)))
#define WAITVM0 asm volatile("s_waitcnt vmcnt(0)" ::: "memory")
#define WAITVM2 asm volatile("s_waitcnt vmcnt(2)" ::: "memory")
#define WAITVM3 asm volatile("s_waitcnt vmcnt(3)" ::: "memory")

// ws layout (bytes) — identical total footprint to the proven baseline (56,770,560 B)
#define WS_BP    0                 // packed B: 8 nt * 2064 kt * 64 lane * 8 halves * 2B = 16908288
#define WS_XH    16908288          // + 8192*256*2 = 4194304
#define WS_LT    21102592          // + 129*8192*2 = 2113536
#define WS_PARTS 23216128          // + 4 * 8192*256*4 = 33554432  -> total 56770560

// ---------------- K1 (fused prep) — unchanged from R7 (coalesced, proven).
#define PR_T1   516
#define PR_L1   580
#define PR_X1   1604
#define PR_O1   1608
#define PR_B1   2632
__global__ void k_prep(const float* __restrict__ Ww, const float* __restrict__ bw,
                       const float* __restrict__ x,  const float* __restrict__ latent,
                       const float* __restrict__ Wb, const float* __restrict__ bb,
                       _Float16* __restrict__ Bp, _Float16* __restrict__ Xh,
                       _Float16* __restrict__ LT, float* __restrict__ part0) {
    __shared__ _Float16 smemh[16512];       // 33024 B
    const int bid = blockIdx.x;
    const int t   = threadIdx.x;

    if (bid < PR_T1) {
        // ---- W transpose + pack. tile[64][256] f16 = 32KB.
        _Float16* tile = smemh;
        const int k0 = bid * 64;
#pragma unroll
        for (int j = 0; j < 16; ++j) {
            int idx = j * 256 + t;          // 4096 float4 slots = 64 rows x 64 f4
            int row = idx >> 6, col = (idx & 63) * 4;
            int k = k0 + row;
            const float* src = (k < LAT_N * IN_N)
                             ? Ww + (size_t)k * 256 + col
                             : bw + (size_t)(k - LAT_N * IN_N) * 256 + col;
            float4 v = *(const float4*)src;
            h4 o;
            o[0] = (_Float16)v.x; o[1] = (_Float16)v.y;
            o[2] = (_Float16)v.z; o[3] = (_Float16)v.w;
            *(h4*)(tile + row * 256 + col) = o;
        }
        __syncthreads();
        const int tl = t & 31;
#pragma unroll
        for (int j = 0; j < 4; ++j) {
            int stid = j * 8 + (t >> 5);    // 0..31 subtiles
            int kt_l = stid >> 3, nt = stid & 7;
            int kt16 = bid * 4 + kt_l;
            _Float16* dst = Bp + ((size_t)(nt * KT16 + kt16) * 64) * 8;
#pragma unroll
            for (int kh = 0; kh < 2; ++kh) {
                h8 v;
#pragma unroll
                for (int h = 0; h < 8; ++h)
                    v[h] = tile[(kt_l * 16 + kh * 8 + h) * 256 + nt * 32 + tl];
                *(h8*)(dst + (size_t)(kh * 32 + tl) * 8) = v;
            }
        }
    } else if (bid < PR_L1) {
        // ---- latent transpose via 128x129 LDS tile
        _Float16* t2 = smemh;
        const int b0 = (bid - PR_T1) * 128;
#pragma unroll
        for (int j = 0; j < 16; ++j) {
            int idx = j * 256 + t;          // 4096 float4 slots = 128 b-rows x 32 f4
            int b = idx >> 5, l = (idx & 31) * 4;
            float4 v = *(const float4*)(latent + (size_t)(b0 + b) * 128 + l);
            t2[(l + 0) * 129 + b] = (_Float16)v.x;
            t2[(l + 1) * 129 + b] = (_Float16)v.y;
            t2[(l + 2) * 129 + b] = (_Float16)v.z;
            t2[(l + 3) * 129 + b] = (_Float16)v.w;
        }
        __syncthreads();
#pragma unroll
        for (int j = 0; j < 32; ++j) {
            int idx = j * 256 + t;          // 8192 h2 slots = 128 l-rows x 64 h2
            int l = idx >> 6, bb2 = (idx & 63) * 2;
            h2 w;
            w[0] = t2[l * 129 + bb2];
            w[1] = t2[l * 129 + bb2 + 1];
            *(h2*)(LT + (size_t)l * BATCH + b0 + bb2) = w;
        }
    } else if (bid < PR_X1) {
        // ---- x -> f16, 8 elems/thread
        const int cb = bid - PR_L1;
        int i = (cb * 256 + t) * 8;
        float4 v0 = *(const float4*)(x + i);
        float4 v1 = *(const float4*)(x + i + 4);
        h8 o;
        o[0] = (_Float16)v0.x; o[1] = (_Float16)v0.y;
        o[2] = (_Float16)v0.z; o[3] = (_Float16)v0.w;
        o[4] = (_Float16)v1.x; o[5] = (_Float16)v1.y;
        o[6] = (_Float16)v1.z; o[7] = (_Float16)v1.w;
        *(h8*)(Xh + i) = o;
    } else if (bid < PR_O1) {
        // ---- ones row l=128 of LT
        const int ob = bid - PR_X1;
        int base = ob * 2048 + t * 8;
        h8 o;
#pragma unroll
        for (int h = 0; h < 8; ++h) o[h] = (_Float16)1.0f;
        *(h8*)(LT + (size_t)LAT_N * BATCH + base) = o;
    } else {
        // ---- bias into split-0 partial
        float* lat = (float*)smemh;         // [8][128] f32 = 4KB
        const int b0 = (bid - PR_O1) * 8;   // 1024 blocks
#pragma unroll
        for (int j = 0; j < 4; ++j) {
            int idx = t + 256 * j;          // 0..1023
            int rr = idx >> 7, l = idx & 127;
            lat[rr * 128 + l] = latent[(size_t)(b0 + rr) * 128 + l];
        }
        __syncthreads();
        const int o = t;
        float acc[8];
        float bbv = bb[o];
#pragma unroll
        for (int rr = 0; rr < 8; ++rr) acc[rr] = bbv;
        for (int l = 0; l < 128; ++l) {
            float w = Wb[l * 256 + o];
#pragma unroll
            for (int rr = 0; rr < 8; ++rr) acc[rr] += lat[rr * 128 + l] * w;
        }
#pragma unroll
        for (int rr = 0; rr < 8; ++rr) part0[(size_t)(b0 + rr) * 256 + o] = acc[rr];
    }
}

// ---------------- K2: main GEMM, BM=128 pipeline rewrite.
// WHY BM=128: at BM=64, B L2 traffic = 512 blocks x 4.2MB = 2.16GB -> needs 33.7 TB/s
// (=L2 ceiling) at the 64us MFMA floor: MFMA and L2 saturate TOGETHER at ~40%.
// BM=128 halves it (17 TB/s at MFMA-bound -> feasible).
// Geometry: 512 thr (8 waves, 4M x 2N), wave tile 32 rows x 128 cols:
//   A: 16 x h8 = 64 VGPR, IN REGISTERS (no A-LDS, no A ds_reads in loop)
//   acc: 4 x f16v = 64 AGPR;  total ~170 regs < 256 budget at (512,2) [R1/R2 regime]
// B: 4-buffer LDS ring (4 x 16KB = 64KB static), staged via global_load_lds
// (wave-uniform dest + lane*16), counted vmcnt(2) per step (never 0 -> stage of
// step s+2 stays in flight across barriers, T3/T4 recipe). 4 buffers => buffer
// index (step%4) is STATIC inside the unrolled 8-step slab body (rule #20).
// Slab-start steps use vmcnt(3): the per-slab latent-scalar load adds 1 VM op;
// vmcnt(3) drains both loads of stage[s+1] under any compiler issue order.
// Grid 256 = 64 m x 4 ks -> 1 block/CU (LDS+regs), 2 waves/SIMD.
__global__ __launch_bounds__(512, 2) void k_gemm(const _Float16* __restrict__ Bp,
                                                 const _Float16* __restrict__ Xh,
                                                 const _Float16* __restrict__ LT,
                                                 float* __restrict__ parts) {
    __shared__ __align__(16) _Float16 Bs[4 * 8192];   // 64 KB: 4 bufs x (2 kt16 x 8 nt x 1KB)

    const int bid   = blockIdx.x;           // 256 blocks
    const int ks    = bid & 3;
    const int m_blk = bid >> 2;             // 0..63
    const int m0    = m_blk * 128;
    const int slab0 = (ks == 0) ? 0 : 33 + 32 * (ks - 1);
    const int nslab = (ks == 0) ? 33 : 32;  // 33 + 3*32 = 129

    const int tid = threadIdx.x, wid = tid >> 6, lane = tid & 63;
    const int l32 = lane & 31, khalf = lane >> 5;
    const int wm = wid >> 1, wn = wid & 1;  // 4M x 2N wave grid
    const int wn4 = wn * 4;                 // nt base for this wave's 128 cols
    const int mrow = m0 + wm * 32 + l32;    // this lane's A row

    // ---- A fragment rows into registers (16 k16-tiles x h8)
    h8 xv[16];
    const _Float16* xp = Xh + (size_t)mrow * IN_N + khalf * 8;
#pragma unroll
    for (int k = 0; k < 16; ++k) xv[k] = *(const h8*)(xp + k * 16);

    // latent scalar for slab 0
    const _Float16* ltp = LT + (size_t)slab0 * BATCH;
    _Float16 s_cur = ltp[mrow];

    // ---- B staging setup: 16 chunks/step (kt_l in {0,1} x nt in 0..7), 2 per wave
    const int chunk0 = wid * 2;
    const int ktl0 = chunk0 >> 3, nt0 = chunk0 & 7;
    const char* Bgb = (const char*)Bp;

#define STAGE(bufidx, ktg)                                                                 \
    do {                                                                                   \
        const char* g0_ = Bgb + (((size_t)(nt0 * KT16 + (ktg) + ktl0)) << 10) + (lane << 4);     \
        const char* g1_ = Bgb + (((size_t)((nt0 + 1) * KT16 + (ktg) + ktl0)) << 10) + (lane << 4); \
        _Float16* l0_ = Bs + (bufidx) * 8192 + chunk0 * 512;                               \
        __builtin_amdgcn_global_load_lds((const AS1 void*)g0_, (AS3 void*)l0_, 16, 0, 0);  \
        __builtin_amdgcn_global_load_lds((const AS1 void*)g1_, (AS3 void*)(l0_ + 512), 16, 0, 0); \
    } while (0)

    f16v acc0, acc1, acc2, acc3;
#pragma unroll
    for (int r = 0; r < 16; ++r) { acc0[r] = 0.f; acc1[r] = 0.f; acc2[r] = 0.f; acc3[r] = 0.f; }

#define KSTEP(bufc, sl)                                                                    \
    _Pragma("unroll")                                                                      \
    for (int j = 0; j < 2; ++j) {                                                          \
        const int kx = (((sl) * 2 + j) & 15);                                              \
        h8 a = xv[kx] * s8;                                                                \
        const _Float16* bb = Bs + (bufc) * 8192 + j * 4096 + wn4 * 512 + (lane << 3);      \
        h8 b0 = *(const h8*)(bb);                                                          \
        h8 b1 = *(const h8*)(bb + 512);                                                    \
        h8 b2 = *(const h8*)(bb + 1024);                                                   \
        h8 b3 = *(const h8*)(bb + 1536);                                                   \
        acc0 = __builtin_amdgcn_mfma_f32_32x32x16_f16(a, b0, acc0, 0, 0, 0);               \
        acc1 = __builtin_amdgcn_mfma_f32_32x32x16_f16(a, b1, acc1, 0, 0, 0);               \
        acc2 = __builtin_amdgcn_mfma_f32_32x32x16_f16(a, b2, acc2, 0, 0, 0);               \
        acc3 = __builtin_amdgcn_mfma_f32_32x32x16_f16(a, b3, acc3, 0, 0, 0);               \
    }

    const int kb = slab0 * 16;              // base kt16 of this K-split

    // ---- prologue: stage steps 0,1 into bufs 0,1; wait buf0 complete
    STAGE(0, kb + 0);
    STAGE(1, kb + 2);
    WAITVM2;
    __builtin_amdgcn_s_barrier();
    asm volatile("" ::: "memory");

    // ---- main loop: slabs 0 .. nslab-2 (stages always valid, LT prefetch each slab)
    for (int s0 = 0; s0 < nslab - 1; ++s0) {
        _Float16 s_nx = ltp[(size_t)(s0 + 1) * BATCH + mrow];   // 1 VM op (covered by vmcnt(3))
        h8 s8;
#pragma unroll
        for (int h = 0; h < 8; ++h) s8[h] = s_cur;
        const int ktg0 = kb + s0 * 16;
#pragma unroll
        for (int sl = 0; sl < 8; ++sl) {
            STAGE((sl + 2) & 3, ktg0 + (sl + 2) * 2);
            KSTEP(sl & 3, sl);
            if (sl == 0) WAITVM3; else WAITVM2;
            __builtin_amdgcn_s_barrier();
            asm volatile("" ::: "memory");
        }
        s_cur = s_nx;
    }

    // ---- last slab (peeled): no stages past the end, drain at sl==6
    {
        h8 s8;
#pragma unroll
        for (int h = 0; h < 8; ++h) s8[h] = s_cur;
        const int ktg0 = kb + (nslab - 1) * 16;
#pragma unroll
        for (int sl = 0; sl < 8; ++sl) {
            if (sl < 6) STAGE((sl + 2) & 3, ktg0 + (sl + 2) * 2);
            KSTEP(sl & 3, sl);
            if (sl < 7) {
                if (sl == 6) WAITVM0; else WAITVM2;
                __builtin_amdgcn_s_barrier();
                asm volatile("" ::: "memory");
            }
        }
    }

    // ---- epilogue: write partials; split 0 accumulates onto pre-written bias
    float* dst = parts + (size_t)ks * ((size_t)BATCH * OUT_N);
    const int rowb = m0 + wm * 32;
#define EPI(u, accv)                                                                       \
    {                                                                                      \
        int col = wn * 128 + (u) * 32 + l32;                                               \
        _Pragma("unroll")                                                                  \
        for (int r = 0; r < 16; ++r) {                                                     \
            int row = rowb + (r & 3) + 8 * (r >> 2) + 4 * khalf;                           \
            size_t off = (size_t)row * OUT_N + col;                                        \
            if (ks == 0) dst[off] += accv[r];                                              \
            else         dst[off] = accv[r];                                               \
        }                                                                                  \
    }
    EPI(0, acc0); EPI(1, acc1); EPI(2, acc2); EPI(3, acc3);
#undef EPI
#undef KSTEP
#undef STAGE
}

// ---------------- K3: out = sum of 4 partials
__global__ void k_reduce(const float* __restrict__ parts, float* __restrict__ out) {
    int i = (blockIdx.x * 256 + threadIdx.x) * 4;
    f4v s = *(const f4v*)(parts + i);
    s += *(const f4v*)(parts + 2097152 + i);
    s += *(const f4v*)(parts + 2 * 2097152 + i);
    s += *(const f4v*)(parts + 3 * 2097152 + i);
    *(f4v*)(out + i) = s;
}

extern "C" void kernel_launch(void* const* d_in, const int* in_sizes, int n_in,
                              void* d_out, int out_size, void* d_ws, size_t ws_size,
                              hipStream_t stream) {
    const float* x      = (const float*)d_in[0];
    const float* latent = (const float*)d_in[1];
    const float* Ww     = (const float*)d_in[2];
    const float* bw     = (const float*)d_in[3];
    const float* Wb     = (const float*)d_in[4];
    const float* bb     = (const float*)d_in[5];

    char* ws = (char*)d_ws;
    _Float16* Bp    = (_Float16*)(ws + WS_BP);
    _Float16* Xh    = (_Float16*)(ws + WS_XH);
    _Float16* LT    = (_Float16*)(ws + WS_LT);
    float*    parts = (float*)(ws + WS_PARTS);
    float*    out   = (float*)d_out;

    k_prep<<<PR_B1, 256, 0, stream>>>(Ww, bw, x, latent, Wb, bb, Bp, Xh, LT, parts);
    k_gemm<<<256, 512, 0, stream>>>(Bp, Xh, LT, parts);
    k_reduce<<<2048, 256, 0, stream>>>(parts, out);
}